// Round 1
// baseline (1516.419 us; speedup 1.0000x reference)
//
#include <hip/hip_runtime.h>

#define BB 2048
#define TT 2048
#define II 8
#define HH 24
#define NB 8                 // batches per workgroup
#define NTHR 256
#define VEC_STRIDE 36        // floats per batch vec (32 used); 144B, 16B-aligned
#define PP_STRIDE 28         // predpart stride; 112B, 16B-aligned

__global__ __launch_bounds__(NTHR)
void lstm_anom_kernel(const float* __restrict__ x,
                      const float* __restrict__ W_ih,
                      const float* __restrict__ W_hh,
                      const float* __restrict__ b_ih,
                      const float* __restrict__ b_hh,
                      const float* __restrict__ W_out,
                      const float* __restrict__ b_out,
                      float* __restrict__ out)
{
    __shared__ __align__(16) float vec[2][NB][VEC_STRIDE];   // [inp(8); h(24)] ping-pong
    __shared__ __align__(16) float ppart[NB][PP_STRIDE];     // W_out[j]*h[j] partials
    __shared__ float x0buf[NB];                              // x[b][t+1][0]
    __shared__ __align__(16) float pchunk[2][NB][32];        // pred history, ping-pong

    const int tid = threadIdx.x;
    const int b0  = blockIdx.x * NB;

    const bool isUnit = (tid < NB * HH);      // 192 unit lanes
    const int  ub = tid / HH;                 // 0..7
    const int  uj = tid - ub * HH;            // 0..23
    const bool isX = (tid >= 192);            // 64 x lanes
    const int  xb = (tid - 192) >> 3;         // 0..7
    const int  xk = (tid - 192) & 7;          // 0..7
    const bool isPred = (tid < NB);           // 8 pred lanes (also unit lanes)

    // ---- persistent per-lane state ----
    float w[4][32];
    float bias[4];
    float cst = 0.f;
    float woutj = 0.f;
    if (isUnit) {
        #pragma unroll
        for (int g = 0; g < 4; ++g) {
            const int row = g * HH + uj;
            #pragma unroll
            for (int k = 0; k < II; ++k) w[g][k] = W_ih[row * II + k];
            #pragma unroll
            for (int k = 0; k < HH; ++k) w[g][8 + k] = W_hh[row * HH + k];
            bias[g] = b_ih[row] + b_hh[row];
        }
        woutj = W_out[uj];
    }
    const float bout = b_out[0];

    // ---- init: vec[0] = [x[b][0][:8]; h0=0] ----
    for (int i = tid; i < NB * VEC_STRIDE; i += NTHR) {
        const int b = i / VEC_STRIDE, k = i - b * VEC_STRIDE;
        float v = 0.f;
        if (k < II) v = x[(size_t)(b0 + b) * TT * II + k];
        vec[0][b][k] = v;
    }
    // x pipeline: xA holds x[b][t+1][k] at top of step t
    float xA = 0.f, xB = 0.f;
    if (isX) xA = x[(size_t)(b0 + xb) * TT * II + (size_t)1 * II + xk];
    __syncthreads();

    for (int t = 0; t < TT; ++t) {
        const int p  = t & 1;
        const int pc = (t >> 5) & 1;

        // coalesced flush of previous 32 preds
        if (t > 0 && (t & 31) == 0) {
            const int tt = tid & 31, fb = tid >> 5;
            out[(size_t)(b0 + fb) * TT + (t - 32) + tt] = pchunk[pc ^ 1][fb][tt];
        }

        if (isUnit) {
            // read [inp; h] (broadcast within batch group)
            float v[32];
            const float* vp = vec[p][ub];
            #pragma unroll
            for (int c = 0; c < 8; ++c) {
                const float4 q = *reinterpret_cast<const float4*>(vp + c * 4);
                v[c * 4 + 0] = q.x; v[c * 4 + 1] = q.y;
                v[c * 4 + 2] = q.z; v[c * 4 + 3] = q.w;
            }
            float a0 = bias[0], a1 = bias[1], a2 = bias[2], a3 = bias[3];
            #pragma unroll
            for (int k = 0; k < 32; ++k) {
                a0 = fmaf(w[0][k], v[k], a0);
                a1 = fmaf(w[1][k], v[k], a1);
                a2 = fmaf(w[2][k], v[k], a2);
                a3 = fmaf(w[3][k], v[k], a3);
            }
            const float ig = 1.f / (1.f + __expf(-a0));
            const float fg = 1.f / (1.f + __expf(-a1));
            const float gg = 1.f - 2.f / (1.f + __expf(2.f * a2));   // tanh
            const float og = 1.f / (1.f + __expf(-a3));
            cst = fg * cst + ig * gg;
            const float tc = 1.f - 2.f / (1.f + __expf(2.f * cst)); // tanh(c)
            const float h  = og * tc;
            vec[p ^ 1][ub][8 + uj] = h;
            ppart[ub][uj] = woutj * h;
        }
        if (isX) {
            if (xk > 0) vec[p ^ 1][xb][xk] = xA;
            else        x0buf[xb] = xA;
            int tn = t + 2; if (tn > TT - 1) tn = TT - 1;
            xB = x[(size_t)(b0 + xb) * TT * II + (size_t)tn * II + xk];
        }
        __syncthreads();

        if (isPred) {
            const int b = tid;
            float s = 0.f;
            #pragma unroll
            for (int c = 0; c < 6; ++c) {
                const float4 q = *reinterpret_cast<const float4*>(&ppart[b][c * 4]);
                s += q.x + q.y + q.z + q.w;
            }
            const float pred = s + bout;
            pchunk[pc][b][t & 31] = pred;
            const float xn = x0buf[b];
            const float in0 = (fabsf(pred - xn) > 0.1f) ? pred : xn;
            vec[p ^ 1][b][0] = in0;
        }
        if (isX) xA = xB;
        __syncthreads();
    }

    // final flush (preds for t in [T-32, T))
    {
        const int tt = tid & 31, fb = tid >> 5;
        out[(size_t)(b0 + fb) * TT + (TT - 32) + tt] = pchunk[((TT >> 5) - 1) & 1][fb][tt];
    }
}

extern "C" void kernel_launch(void* const* d_in, const int* in_sizes, int n_in,
                              void* d_out, int out_size, void* d_ws, size_t ws_size,
                              hipStream_t stream) {
    const float* x     = (const float*)d_in[0];
    const float* W_ih  = (const float*)d_in[1];
    const float* W_hh  = (const float*)d_in[2];
    const float* b_ih  = (const float*)d_in[3];
    const float* b_hh  = (const float*)d_in[4];
    const float* W_out = (const float*)d_in[5];
    const float* b_out = (const float*)d_in[6];
    float* out = (float*)d_out;

    dim3 grid(BB / NB);   // 256 workgroups
    dim3 block(NTHR);     // 256 threads
    lstm_anom_kernel<<<grid, block, 0, stream>>>(x, W_ih, W_hh, b_ih, b_hh,
                                                 W_out, b_out, out);
}

// Round 2
// 1491.475 us; speedup vs baseline: 1.0167x; 1.0167x over previous
//
#include <hip/hip_runtime.h>

#define TT 2048
#define II 8
#define HH 24
#define THRESH 0.1f

// One wave (64 lanes) per batch element.
// Lanes 0-23   : units j=0..23, LOW half of dot (k=0..15 -> [inp(8); h0..h7])
// Lanes 32-55  : units j=0..23, HIGH half of dot (k=16..31 -> [h8..h23])
// Lanes 24-31  : x-prefetch lanes (k=0..7), also participate in shuffles with 0
// Lanes 56-63  : idle (benign junk, masked out of reductions by woutj=0)
//
// Per step: 64 FMA/lane, gate halves combined via shfl_xor(32); W_out head is a
// 5-step shfl_xor reduction (pred lands in every lane -> anomaly select in
// registers, no LDS round-trip, no second barrier). h/x exchange: one
// ds_write_b32 (banks 0..31, conflict-free) + 4 broadcast ds_read_b128.

__global__ __launch_bounds__(64)
void lstm_anom_kernel(const float* __restrict__ x,
                      const float* __restrict__ W_ih,
                      const float* __restrict__ W_hh,
                      const float* __restrict__ b_ih,
                      const float* __restrict__ b_hh,
                      const float* __restrict__ W_out,
                      const float* __restrict__ b_out,
                      float* __restrict__ out)
{
    __shared__ __align__(16) float vbuf[32];   // [x0raw, x1..x7, h0..h23]

    const int  lane  = threadIdx.x;
    const int  b     = blockIdx.x;
    const int  l32   = lane & 31;
    const bool hi    = lane >= 32;
    const bool unitL = (l32 < HH);
    const int  j     = unitL ? l32 : 0;        // clamped (junk lanes load row 0)
    const bool xL    = (!hi) && (l32 >= 24);   // lanes 24..31
    const int  xk    = l32 - 24;

    const float* xb = x + (size_t)b * (TT * II);

    // ---- persistent weights: 4 gates x 16-wide half-dot per lane ----
    float w[4][16], bias[4];
    #pragma unroll
    for (int g = 0; g < 4; ++g) {
        const int row = g * HH + j;
        if (!hi) {
            #pragma unroll
            for (int k = 0; k < 8; ++k) w[g][k] = W_ih[row * II + k];
            #pragma unroll
            for (int k = 0; k < 8; ++k) w[g][8 + k] = W_hh[row * HH + k];
            bias[g] = b_ih[row] + b_hh[row];
        } else {
            #pragma unroll
            for (int k = 0; k < 16; ++k) w[g][k] = W_hh[row * HH + 8 + k];
            bias[g] = 0.f;
        }
    }
    const float woutj = unitL ? W_out[j] : 0.f;  // 0 masks junk lanes out of pred
    const float bout  = b_out[0];

    // ---- init: vbuf = [x[b][0][:8]; h0 = 0] (pred0==actual -> no substitution)
    if (lane < 32) vbuf[lane] = (lane < 8) ? xb[lane] : 0.f;
    float xA = 0.f, xB = 0.f;
    if (xL) xA = xb[II + xk];                  // x[b][1][k]
    __syncthreads();

    const int vbase = hi ? 16 : 0;
    float v[16];
    {
        const float4 q0 = *(const float4*)&vbuf[vbase + 0];
        const float4 q1 = *(const float4*)&vbuf[vbase + 4];
        const float4 q2 = *(const float4*)&vbuf[vbase + 8];
        const float4 q3 = *(const float4*)&vbuf[vbase + 12];
        v[0]=q0.x; v[1]=q0.y; v[2]=q0.z; v[3]=q0.w;
        v[4]=q1.x; v[5]=q1.y; v[6]=q1.z; v[7]=q1.w;
        v[8]=q2.x; v[9]=q2.y; v[10]=q2.z; v[11]=q2.w;
        v[12]=q3.x; v[13]=q3.y; v[14]=q3.z; v[15]=q3.w;
    }

    float c = 0.f, predsave = 0.f;

    for (int t = 0; t < TT; ++t) {
        // ---- 4 gate half-dots (16 FMAs each), combine halves via xor-32 ----
        float a0 = bias[0], a1 = bias[1], a2 = bias[2], a3 = bias[3];
        #pragma unroll
        for (int k = 0; k < 16; ++k) {
            a0 = fmaf(w[0][k], v[k], a0);
            a1 = fmaf(w[1][k], v[k], a1);
            a2 = fmaf(w[2][k], v[k], a2);
            a3 = fmaf(w[3][k], v[k], a3);
        }
        a0 += __shfl_xor(a0, 32, 64);
        a1 += __shfl_xor(a1, 32, 64);
        a2 += __shfl_xor(a2, 32, 64);
        a3 += __shfl_xor(a3, 32, 64);

        const float ig = 1.f / (1.f + __expf(-a0));
        const float fg = 1.f / (1.f + __expf(-a1));
        const float gg = 1.f - 2.f / (1.f + __expf(2.f * a2));   // tanh
        const float og = 1.f / (1.f + __expf(-a3));
        c = fg * c + ig * gg;
        const float tc = 1.f - 2.f / (1.f + __expf(2.f * c));    // tanh(c)
        const float h  = og * tc;

        // ---- head: pred = sum_j wout_j*h_j + b_out, in-register reduction ----
        float p = woutj * h;
        p += __shfl_xor(p, 16, 64);
        p += __shfl_xor(p, 8, 64);
        p += __shfl_xor(p, 4, 64);
        p += __shfl_xor(p, 2, 64);
        p += __shfl_xor(p, 1, 64);
        const float pred = p + bout;

        // buffer pred in the matching lane; coalesced 256B flush every 64 steps
        predsave = ((t & 63) == lane) ? pred : predsave;
        if ((t & 63) == 63) out[(size_t)b * TT + (t - 63) + lane] = predsave;

        // ---- stage next step's inputs: banks 0..31, conflict-free ----
        if (lane < 32) vbuf[xL ? xk : (8 + l32)] = xL ? xA : h;
        if (xL) {
            int tn = t + 2; if (tn > TT - 1) tn = TT - 1;
            xB = xb[(size_t)tn * II + xk];
        }
        __syncthreads();

        float4 q0 = *(const float4*)&vbuf[vbase + 0];
        const float4 q1 = *(const float4*)&vbuf[vbase + 4];
        const float4 q2 = *(const float4*)&vbuf[vbase + 8];
        const float4 q3 = *(const float4*)&vbuf[vbase + 12];
        if (!hi) {  // anomaly substitution on input 0, in registers
            q0.x = (fabsf(pred - q0.x) > THRESH) ? pred : q0.x;
        }
        v[0]=q0.x; v[1]=q0.y; v[2]=q0.z; v[3]=q0.w;
        v[4]=q1.x; v[5]=q1.y; v[6]=q1.z; v[7]=q1.w;
        v[8]=q2.x; v[9]=q2.y; v[10]=q2.z; v[11]=q2.w;
        v[12]=q3.x; v[13]=q3.y; v[14]=q3.z; v[15]=q3.w;

        if (xL) xA = xB;
    }
}

extern "C" void kernel_launch(void* const* d_in, const int* in_sizes, int n_in,
                              void* d_out, int out_size, void* d_ws, size_t ws_size,
                              hipStream_t stream) {
    const float* x     = (const float*)d_in[0];
    const float* W_ih  = (const float*)d_in[1];
    const float* W_hh  = (const float*)d_in[2];
    const float* b_ih  = (const float*)d_in[3];
    const float* b_hh  = (const float*)d_in[4];
    const float* W_out = (const float*)d_in[5];
    const float* b_out = (const float*)d_in[6];
    float* out = (float*)d_out;

    dim3 grid(2048);   // one wave per batch element
    dim3 block(64);
    lstm_anom_kernel<<<grid, block, 0, stream>>>(x, W_ih, W_hh, b_ih, b_hh,
                                                 W_out, b_out, out);
}

// Round 4
// 1309.666 us; speedup vs baseline: 1.1579x; 1.1388x over previous
//
#include <hip/hip_runtime.h>

#define TT 2048
#define II 8
#define HH 24
#define THRESH 0.1f

// lo+hi half sums replicated to all 64 lanes (VALU-only, replaces shfl_xor 32)
__device__ __forceinline__ float fold_xor32(float a) {
    auto r = __builtin_amdgcn_permlane32_swap(__float_as_int(a), __float_as_int(a),
                                              false, false);
    return __int_as_float(r[0]) + __int_as_float(r[1]);
}
// fold across the two 16-rows of each 32-half (VALU-only)
__device__ __forceinline__ float fold_xor16(float a) {
    auto r = __builtin_amdgcn_permlane16_swap(__float_as_int(a), __float_as_int(a),
                                              false, false);
    return __int_as_float(r[0]) + __int_as_float(r[1]);
}
// rotate within 16-lane row by N, add (DPP row_ror, VALU-only)
#define ROR_ADD(a, N)                                                          \
    {                                                                          \
        int t_ = __builtin_amdgcn_update_dpp(0, __float_as_int(a),             \
                                             0x120 + (N), 0xF, 0xF, false);    \
        (a) += __int_as_float(t_);                                             \
    }

// One wave (64 lanes) per batch element.
// Lanes 0-23  : units j=0..23, LOW half dot  (k=0..15 -> [in0,x1..7,h0..7])
// Lanes 32-55 : units j=0..23, HIGH half dot (k=16..31 -> [h8..h23])
// Lanes 24-31 : x prefetch (k=0..7). Lanes 56-63: benign junk (woutj=0).
__global__ __launch_bounds__(64)
void lstm_anom_kernel(const float* __restrict__ x,
                      const float* __restrict__ W_ih,
                      const float* __restrict__ W_hh,
                      const float* __restrict__ b_ih,
                      const float* __restrict__ b_hh,
                      const float* __restrict__ W_out,
                      const float* __restrict__ b_out,
                      float* __restrict__ out)
{
    __shared__ __align__(16) float vbuf[32];   // [x0raw, x1..x7, h0..h23]

    const int  lane  = threadIdx.x;
    const int  b     = blockIdx.x;
    const int  l32   = lane & 31;
    const bool hi    = lane >= 32;
    const bool unitL = (l32 < HH);
    const int  j     = unitL ? l32 : 0;
    const bool xL    = (!hi) && (l32 >= 24);
    const int  xk    = l32 - 24;

    const float* xb = x + (size_t)b * (TT * II);

    // ---- persistent weights: 4 gates x 16-wide half-dot per lane (as R2) ----
    float w[4][16], bias[4];
    #pragma unroll
    for (int g = 0; g < 4; ++g) {
        const int row = g * HH + j;
        if (!hi) {
            #pragma unroll
            for (int k = 0; k < 8; ++k) w[g][k] = W_ih[row * II + k];
            #pragma unroll
            for (int k = 0; k < 8; ++k) w[g][8 + k] = W_hh[row * HH + k];
            bias[g] = b_ih[row] + b_hh[row];
        } else {
            #pragma unroll
            for (int k = 0; k < 16; ++k) w[g][k] = W_hh[row * HH + 8 + k];
            bias[g] = 0.f;
        }
    }
    const float woutj = unitL ? W_out[j] : 0.f;
    const float bout  = b_out[0];

    // ---- init: vbuf = [x[b][0][:8]; h0 = 0] ----
    if (lane < 32) vbuf[lane] = (lane < 8) ? xb[lane] : 0.f;
    float xA = 0.f, xB = 0.f;
    if (xL) xA = xb[II + xk];                  // x[b][1][k]
    __syncthreads();

    const int vbase = hi ? 16 : 0;
    float v[16];
    {
        const float4 q0 = *(const float4*)&vbuf[vbase + 0];
        const float4 q1 = *(const float4*)&vbuf[vbase + 4];
        const float4 q2 = *(const float4*)&vbuf[vbase + 8];
        const float4 q3 = *(const float4*)&vbuf[vbase + 12];
        v[0]=q0.x; v[1]=q0.y; v[2]=q0.z; v[3]=q0.w;
        v[4]=q1.x; v[5]=q1.y; v[6]=q1.z; v[7]=q1.w;
        v[8]=q2.x; v[9]=q2.y; v[10]=q2.z; v[11]=q2.w;
        v[12]=q3.x; v[13]=q3.y; v[14]=q3.z; v[15]=q3.w;
    }

    float c = 0.f, predsave = 0.f;

    for (int t = 0; t < TT; ++t) {
        // ---- 4 gate half-dots, EXACT R2 order (serial scalar FMA) ----
        float a0 = bias[0], a1 = bias[1], a2 = bias[2], a3 = bias[3];
        #pragma unroll
        for (int k = 0; k < 16; ++k) {
            a0 = fmaf(w[0][k], v[k], a0);
            a1 = fmaf(w[1][k], v[k], a1);
            a2 = fmaf(w[2][k], v[k], a2);
            a3 = fmaf(w[3][k], v[k], a3);
        }
        const float A0 = fold_xor32(a0);
        const float A1 = fold_xor32(a1);
        const float A2 = fold_xor32(a2);
        const float A3 = fold_xor32(a3);

        const float ig = 1.f / (1.f + __expf(-A0));
        const float fg = 1.f / (1.f + __expf(-A1));
        const float gg = 1.f - 2.f / (1.f + __expf(2.f * A2));   // tanh
        const float og = 1.f / (1.f + __expf(-A3));
        c = fg * c + ig * gg;
        const float tc = 1.f - 2.f / (1.f + __expf(2.f * c));    // tanh(c)
        const float h  = og * tc;

        // ---- stage next inputs EARLY: ds_write + x prefetch under head VALU
        if (lane < 32) vbuf[xL ? xk : (8 + l32)] = xL ? xA : h;
        if (xL) {
            int tn = t + 2; if (tn > TT - 1) tn = TT - 1;
            xB = xb[(size_t)tn * II + xk];
        }

        // ---- head: Σ_j wout_j*h_j — permlane16 fold + 4 DPP ror-adds ----
        float p = woutj * h;
        p = fold_xor16(p);
        ROR_ADD(p, 8); ROR_ADD(p, 4); ROR_ADD(p, 2); ROR_ADD(p, 1);
        const float pred = p + bout;

        // buffer pred; coalesced 256B flush every 64 steps
        predsave = ((t & 63) == lane) ? pred : predsave;
        if ((t & 63) == 63) out[(size_t)b * TT + (t - 63) + lane] = predsave;

        __syncthreads();

        float4 q0 = *(const float4*)&vbuf[vbase + 0];
        const float4 q1 = *(const float4*)&vbuf[vbase + 4];
        const float4 q2 = *(const float4*)&vbuf[vbase + 8];
        const float4 q3 = *(const float4*)&vbuf[vbase + 12];
        if (!hi) {  // anomaly substitution on input 0, in registers
            q0.x = (fabsf(pred - q0.x) > THRESH) ? pred : q0.x;
        }
        v[0]=q0.x; v[1]=q0.y; v[2]=q0.z; v[3]=q0.w;
        v[4]=q1.x; v[5]=q1.y; v[6]=q1.z; v[7]=q1.w;
        v[8]=q2.x; v[9]=q2.y; v[10]=q2.z; v[11]=q2.w;
        v[12]=q3.x; v[13]=q3.y; v[14]=q3.z; v[15]=q3.w;

        if (xL) xA = xB;
    }
}

extern "C" void kernel_launch(void* const* d_in, const int* in_sizes, int n_in,
                              void* d_out, int out_size, void* d_ws, size_t ws_size,
                              hipStream_t stream) {
    const float* x     = (const float*)d_in[0];
    const float* W_ih  = (const float*)d_in[1];
    const float* W_hh  = (const float*)d_in[2];
    const float* b_ih  = (const float*)d_in[3];
    const float* b_hh  = (const float*)d_in[4];
    const float* W_out = (const float*)d_in[5];
    const float* b_out = (const float*)d_in[6];
    float* out = (float*)d_out;

    dim3 grid(2048);   // one wave per batch element
    dim3 block(64);
    lstm_anom_kernel<<<grid, block, 0, stream>>>(x, W_ih, W_hh, b_ih, b_hh,
                                                 W_out, b_out, out);
}

// Round 5
// 808.064 us; speedup vs baseline: 1.8766x; 1.6207x over previous
//
#include <hip/hip_runtime.h>

#define TT 2048
#define II 8
#define HH 24
#define THRESH 0.1f
#define LOG2E 1.4426950408889634f

// rotate within 16-lane row by N, add (DPP row_ror, VALU-only)
#define ROR_ADD(a, N)                                                          \
    {                                                                          \
        int t_ = __builtin_amdgcn_update_dpp(0, __float_as_int(a),             \
                                             0x120 + (N), 0xF, 0xF, false);    \
        (a) += __int_as_float(t_);                                             \
    }

// One wave per batch element. Uniform-code layout:
//  lane l32=j<24, lo half : owns gate rows (i_j, f_j)  — 2 full 32-wide dots
//  lane l32=j<24, hi half : owns gate rows (g_j, o_j)  — 2 full 32-wide dots
//  lanes 24-31 (lo)       : x prefetch (k=0..7), clamped row-0 weights (junk)
//  lanes 56-63            : junk (clamped row-0 weights), woutj=0
// After nonlinearities, two permlane32_swaps give every lane its unit's
// (ig,fg,gg,og); c,h computed uniformly in all lanes (no divergence, no
// redundant transcendentals per half). Head = permlane16_swap + 4 DPP rors.
__global__ __launch_bounds__(64, 2)
void lstm_anom_kernel(const float* __restrict__ x,
                      const float* __restrict__ W_ih,
                      const float* __restrict__ W_hh,
                      const float* __restrict__ b_ih,
                      const float* __restrict__ b_hh,
                      const float* __restrict__ W_out,
                      const float* __restrict__ b_out,
                      float* __restrict__ out)
{
    __shared__ __align__(16) float vbuf[32];   // [x0raw, x1..x7, h0..h23]

    const int  lane  = threadIdx.x;
    const int  b     = blockIdx.x;
    const int  l32   = lane & 31;
    const bool hi    = lane >= 32;
    const bool unitL = (l32 < HH);
    const int  jc    = unitL ? l32 : 0;        // clamped for junk lanes
    const bool xL    = (!hi) && (l32 >= 24);
    const int  xk    = l32 - 24;

    const float* xb = x + (size_t)b * (TT * II);

    // ---- persistent weights: 2 full gate rows per lane, register-resident ----
    const int rowA = (hi ? 2 * HH : 0) + jc;   // lo: i-gate, hi: g-gate
    const int rowB = rowA + HH;                // lo: f-gate, hi: o-gate
    float wA[32], wB[32];
    #pragma unroll
    for (int k = 0; k < II; ++k) {
        wA[k] = W_ih[rowA * II + k];
        wB[k] = W_ih[rowB * II + k];
    }
    #pragma unroll
    for (int k = 0; k < HH; ++k) {
        wA[II + k] = W_hh[rowA * HH + k];
        wB[II + k] = W_hh[rowB * HH + k];
    }
    const float biasA = b_ih[rowA] + b_hh[rowA];
    const float biasB = b_ih[rowB] + b_hh[rowB];
    // nonlin A: lo -> sigmoid(a), hi -> tanh(a) = 2*sigmoid(2a)-1, uniform code
    const float kA = hi ? (-2.f * LOG2E) : (-LOG2E);
    const float mA = hi ? 2.f : 1.f;
    const float nA = hi ? -1.f : 0.f;
    const float woutj = unitL ? W_out[jc] : 0.f;
    const float bout  = b_out[0];

    // ---- init: vbuf = [x[b][0][:8]; h0 = 0] ----
    if (lane < 32) vbuf[lane] = (lane < 8) ? xb[lane] : 0.f;
    float xA = 0.f, xB = 0.f;
    if (xL) xA = xb[II + xk];                  // x[b][1][k]
    __syncthreads();

    float v[32];
    #pragma unroll
    for (int c8 = 0; c8 < 8; ++c8) {
        const float4 q = *(const float4*)&vbuf[c8 * 4];
        v[c8 * 4 + 0] = q.x; v[c8 * 4 + 1] = q.y;
        v[c8 * 4 + 2] = q.z; v[c8 * 4 + 3] = q.w;
    }
    float pred = v[0];          // pred0 = x[b][0][0] -> no substitution at t=0
    float cst = 0.f, predsave = 0.f;

    for (int t = 0; t < TT; ++t) {
        // anomaly substitution on input 0 (uniform, in registers)
        v[0] = (fabsf(pred - v[0]) > THRESH) ? pred : v[0];

        // ---- 2 full 32-wide gate dots per lane ----
        float aA = biasA, aB = biasB;
        #pragma unroll
        for (int k = 0; k < 32; ++k) {
            aA = fmaf(wA[k], v[k], aA);
            aB = fmaf(wB[k], v[k], aB);
        }

        // ---- nonlinearities, once per gate ----
        const float sA = __builtin_amdgcn_rcpf(1.f + __builtin_amdgcn_exp2f(kA * aA));
        const float tA = fmaf(sA, mA, nA);                  // lo: sig(i), hi: tanh(g)
        const float sB = __builtin_amdgcn_rcpf(1.f + __builtin_amdgcn_exp2f(-LOG2E * aB));
                                                            // lo: sig(f), hi: sig(o)
        // ---- distribute halves: every lane gets its unit's (ig,gg,fg,og) ----
        auto rA = __builtin_amdgcn_permlane32_swap(__float_as_int(tA), __float_as_int(tA), false, false);
        auto rB = __builtin_amdgcn_permlane32_swap(__float_as_int(sB), __float_as_int(sB), false, false);
        const float ig = __int_as_float(rA[0]);
        const float gg = __int_as_float(rA[1]);
        const float fg = __int_as_float(rB[0]);
        const float og = __int_as_float(rB[1]);

        cst = fmaf(fg, cst, ig * gg);
        const float sc = __builtin_amdgcn_rcpf(1.f + __builtin_amdgcn_exp2f(-2.f * LOG2E * cst));
        const float tc = fmaf(2.f, sc, -1.f);               // tanh(c)
        const float h  = og * tc;

        // ---- stage next step's inputs early (banks 0..31, conflict-free) ----
        if (lane < 32) vbuf[xL ? xk : (8 + l32)] = xL ? xA : h;
        if (xL) {
            int tn = t + 2; if (tn > TT - 1) tn = TT - 1;
            xB = xb[(size_t)tn * II + xk];
        }

        // ---- head: Σ_j wout_j*h_j (per 32-half; identical results) ----
        float p = woutj * h;
        {
            auto r = __builtin_amdgcn_permlane16_swap(__float_as_int(p), __float_as_int(p), false, false);
            p = __int_as_float(r[0]) + __int_as_float(r[1]);
        }
        ROR_ADD(p, 8); ROR_ADD(p, 4); ROR_ADD(p, 2); ROR_ADD(p, 1);
        pred = p + bout;

        // buffer pred; coalesced 256B flush every 64 steps
        predsave = ((t & 63) == lane) ? pred : predsave;
        if ((t & 63) == 63) out[(size_t)b * TT + (t - 63) + lane] = predsave;

        __syncthreads();

        // ---- reload v for next step ----
        #pragma unroll
        for (int c8 = 0; c8 < 8; ++c8) {
            const float4 q = *(const float4*)&vbuf[c8 * 4];
            v[c8 * 4 + 0] = q.x; v[c8 * 4 + 1] = q.y;
            v[c8 * 4 + 2] = q.z; v[c8 * 4 + 3] = q.w;
        }
        if (xL) xA = xB;
    }
}

extern "C" void kernel_launch(void* const* d_in, const int* in_sizes, int n_in,
                              void* d_out, int out_size, void* d_ws, size_t ws_size,
                              hipStream_t stream) {
    const float* x     = (const float*)d_in[0];
    const float* W_ih  = (const float*)d_in[1];
    const float* W_hh  = (const float*)d_in[2];
    const float* b_ih  = (const float*)d_in[3];
    const float* b_hh  = (const float*)d_in[4];
    const float* W_out = (const float*)d_in[5];
    const float* b_out = (const float*)d_in[6];
    float* out = (float*)d_out;

    dim3 grid(2048);   // one wave per batch element
    dim3 block(64);
    lstm_anom_kernel<<<grid, block, 0, stream>>>(x, W_ih, W_hh, b_ih, b_hh,
                                                 W_out, b_out, out);
}